// Round 10
// baseline (596.631 us; speedup 1.0000x reference)
//
#include <hip/hip_runtime.h>
#include <math.h>

// Boltzmann Gibbs sweep N=8192, single cooperative kernel.
// 16 blocks of BB=512. WG0 scans block b (8 x 64-step serial sub-scans,
// publishing each sub-del); 255 workers compute panel dots vs private LDS
// state + gather coupling tile AND a 512x64 del7-strip; workers apply
// sub-dels 0..6 incrementally (per-phase flags) and ack after del6 -- i.e.
// DURING WG0's phase 7 -- so the block boundary has no worker round-trip.
// The del7 (previous block) correction is applied by WG0 itself, folded
// into each phase's A-section (strip cols register-prefetched in prior B).
// Cross-WG payloads via agent-scope relaxed (sc1) stores; ordering = vmcnt
// drain at __syncthreads + relaxed flag store. No wbl2/inv on the path.
// Decision: u <= sigmoid(s/T) <=> s >= T*log(u/(1-u)); thr fp64,
// POSITION-indexed (lax.scan zips (perm, rand_u)); clamp/state UNIT-indexed.
// All sums fp64; every correction product w*delta is exact in fp32.

#define NN 8192
#define BB 512
#define NBLK 16
#define SUB 64
#define NSUB 8
#define NWG 256
#define NWORK 255
#define TPB 512
#define MAXR 3
#define MSTR 68                      // padded LDS m-row stride (floats)
#define MBUFW (SUB * MSTR)

typedef unsigned int u32;
typedef unsigned long long u64;

__global__ void k_init(u32* flags, int n) {
  int i = blockIdx.x * blockDim.x + threadIdx.x;
  for (; i < n; i += gridDim.x * blockDim.x) flags[i] = 0;
}

__device__ __forceinline__ u32 ld_rlx(const u32* p) {
  return __hip_atomic_load(p, __ATOMIC_RELAXED, __HIP_MEMORY_SCOPE_AGENT);
}
__device__ __forceinline__ void st_rlx(u32* p, u32 v) {
  __hip_atomic_store(p, v, __ATOMIC_RELAXED, __HIP_MEMORY_SCOPE_AGENT);
}
__device__ __forceinline__ float ldf_rlx(const float* p) {
  return __hip_atomic_load(p, __ATOMIC_RELAXED, __HIP_MEMORY_SCOPE_AGENT);
}
__device__ __forceinline__ void stf_rlx(float* p, float v) {
  __hip_atomic_store(p, v, __ATOMIC_RELAXED, __HIP_MEMORY_SCOPE_AGENT);
}
__device__ __forceinline__ double ldd_rlx(const double* p) {
  return __hip_atomic_load(p, __ATOMIC_RELAXED, __HIP_MEMORY_SCOPE_AGENT);
}
__device__ __forceinline__ void std_rlx(double* p, double v) {
  __hip_atomic_store(p, v, __ATOMIC_RELAXED, __HIP_MEMORY_SCOPE_AGENT);
}

__global__ __launch_bounds__(TPB) void k_gibbs(
    const float* __restrict__ w, const float* __restrict__ init,
    const float* __restrict__ clampv, const float* __restrict__ Tp,
    const int* __restrict__ perm, const float* __restrict__ urand,
    float* __restrict__ dout, double* __restrict__ S,
    float* __restrict__ delG, float* __restrict__ stripG,
    float* __restrict__ tileD, u32* subFlag, u32* ack) {
  __shared__ double poolD[55296 / 8];   // union: WG0 ~53 KB, workers ~33 KB
  const int wg = blockIdx.x, tid = threadIdx.x;
  const int wv = tid >> 6, lane = tid & 63;

  if (wg == 0) {
    double* sumsL = poolD;                                   // 512 f64
    double* thrL  = poolD + BB;                              // 512 f64
    float*  fbase = (float*)(poolD + 2 * BB);
    float*  d1L   = fbase;                                   // 512
    float*  d0L   = fbase + BB;                              // 512
    float*  delL  = fbase + 2 * BB;                          // 512
    float*  oldL  = fbase + 3 * BB;                          // 512
    float*  del7L = fbase + 4 * BB;                          // 64
    int*    uL    = (int*)(fbase + 4 * BB + SUB);            // 512
    float*  mbuf  = fbase + 4 * BB + SUB + BB;               // 2*64*68

    double T = (double)Tp[0];
    float4 nv0, nv1, nv2, nv3;           // near-strip prefetch (waves 4-7)
    float4 sv0, sv1, sv2, sv3;           // del7-strip prefetch (waves 4-7)

    for (int b = 0; b < NBLK; ++b) {
      const bool pub = (b + 1 < NBLK);
      // del7 of previous block -> del7L (delL about to be overwritten)
      if (b > 0 && tid < SUB) del7L[tid] = delL[(NSUB - 1) * SUB + tid];
      // ---- per-block tables (before the ack wait; overlapped) ----
      int pos = b * BB + tid;                    // TPB == BB
      int unit = perm[pos];
      double uu = (double)urand[pos];
      thrL[tid] = T * log(uu / (1.0 - uu));      // u==0 -> -inf -> always 1
      float old = init[unit];
      bool cl = (clampv[unit] != 0.0f);
      d1L[tid] = cl ? 0.0f : (1.0f - old);       // in {0,1}
      d0L[tid] = cl ? 0.0f : (0.0f - old);       // in {0,-1}
      oldL[tid] = old;
      uL[tid] = unit;
      // ---- wait: workers acked block b (S[b] 0..6-corrected, tile+strip in L3)
      {
        const u32* slots = ack + (size_t)b * NWORK;
        for (;;) {
          int ok = 1;
          if (tid < NWORK) ok = (ld_rlx(&slots[tid]) != 0u);
          if (__syncthreads_and(ok)) break;
          __builtin_amdgcn_s_sleep(1);
        }
      }
      sumsL[tid] = ldd_rlx(&S[(size_t)b * BB + tid]);
      if (b > 0 && tid >= 256) {           // strip prefetch for phase 0 rows
        int t = tid - 256;
        const float4* pr = (const float4*)(
            stripG + ((size_t)b * BB + (t >> 2)) * SUB + (t & 3) * 16);
        sv0 = pr[0]; sv1 = pr[1]; sv2 = pr[2]; sv3 = pr[3];
      }
      if (tid >= 448) {                    // wave7: diag(0) of block b -> mbuf[0]
        int l = tid - 448;
        const float4* src = (const float4*)(tileD + (size_t)b * BB * BB + (size_t)l * BB);
        float4* dst = (float4*)(mbuf + l * MSTR);
#pragma unroll
        for (int j = 0; j < 16; ++j) dst[j] = src[j];
      }
      __syncthreads();
      const float* tb = tileD + (size_t)b * BB * BB;

      for (int t8 = 0; t8 < NSUB; ++t8) {
        int o = t8 * SUB;
        float m[SUB];
        // ---------------- A section ----------------
        if (t8 > 0 && pub && tid == 0) st_rlx(&subFlag[b * NSUB + t8 - 1], 1u);
        if (tid < SUB) {
          const float4* mr = (const float4*)(mbuf + (t8 & 1) * MBUFW + tid * MSTR);
#pragma unroll
          for (int j = 0; j < 16; ++j) {
            float4 v = mr[j];
            m[4*j] = v.x; m[4*j+1] = v.y; m[4*j+2] = v.z; m[4*j+3] = v.w;
          }
        } else if (tid >= 256 && (t8 > 0 || b > 0)) {
          // near-pass (del(t8-1)) + del7-prev strip pass, same thread, 16+16 cols
          int t = tid - 256, g_ = t >> 2, q = t & 3;
          int rrow = o + g_;
          double p_ = 0.0;
          if (t8 > 0) {
            int c0 = (t8 - 1) * SUB + q * 16;
            p_ += (double)(nv0.x * delL[c0])    + (double)(nv0.y * delL[c0+1]) +
                  (double)(nv0.z * delL[c0+2])  + (double)(nv0.w * delL[c0+3]) +
                  (double)(nv1.x * delL[c0+4])  + (double)(nv1.y * delL[c0+5]) +
                  (double)(nv1.z * delL[c0+6])  + (double)(nv1.w * delL[c0+7]) +
                  (double)(nv2.x * delL[c0+8])  + (double)(nv2.y * delL[c0+9]) +
                  (double)(nv2.z * delL[c0+10]) + (double)(nv2.w * delL[c0+11]) +
                  (double)(nv3.x * delL[c0+12]) + (double)(nv3.y * delL[c0+13]) +
                  (double)(nv3.z * delL[c0+14]) + (double)(nv3.w * delL[c0+15]);
          }
          if (b > 0) {
            int c0 = q * 16;
            p_ += (double)(sv0.x * del7L[c0])    + (double)(sv0.y * del7L[c0+1]) +
                  (double)(sv0.z * del7L[c0+2])  + (double)(sv0.w * del7L[c0+3]) +
                  (double)(sv1.x * del7L[c0+4])  + (double)(sv1.y * del7L[c0+5]) +
                  (double)(sv1.z * del7L[c0+6])  + (double)(sv1.w * del7L[c0+7]) +
                  (double)(sv2.x * del7L[c0+8])  + (double)(sv2.y * del7L[c0+9]) +
                  (double)(sv2.z * del7L[c0+10]) + (double)(sv2.w * del7L[c0+11]) +
                  (double)(sv3.x * del7L[c0+12]) + (double)(sv3.y * del7L[c0+13]) +
                  (double)(sv3.z * del7L[c0+14]) + (double)(sv3.w * del7L[c0+15]);
          }
          p_ += __shfl_down(p_, 2, 4);
          p_ += __shfl_down(p_, 1, 4);
          if (q == 0) sumsL[rrow] += p_;
        }
        __syncthreads();
        // ---------------- B section ----------------
        if (tid < SUB) {
          // serial 64-step sub-scan: ballot-mask sign-bit chain
          float d1v = d1L[o + tid], d0v = d0L[o + tid];
          u64 P1 = __ballot(d1v != 0.0f);
          u64 M0 = __ballot(d0v != 0.0f);
          double g = sumsL[o + tid] - thrL[o + tid];
          u64 xb = 0ull;
          __builtin_amdgcn_s_setprio(3);
#pragma unroll
          for (int s = 0; s < SUB; ++s) {
            u32 t1 = ((P1 >> s) & 1ull) ? 0x3f800000u : 0u;
            u32 t0 = ((M0 >> s) & 1ull) ? 0xbf800000u : 0u;
            int hi = __builtin_amdgcn_readlane(
                (int)(__double_as_longlong(g) >> 32), s);
            float sdf = __uint_as_float((hi >= 0) ? t1 : t0);
            g += (double)(m[s] * sdf);           // exact fp32 product
            xb |= ((u64)(hi >= 0 ? 1 : 0)) << s;
          }
          __builtin_amdgcn_s_setprio(0);
          float mydel = ((xb >> tid) & 1ull) ? d1v : d0v;
          delL[o + tid] = mydel;
          if (pub) stf_rlx(&delG[b * BB + o + tid], mydel);
        } else if (tid < 128) {
          // wave1: prefetch diag(t8+1) global -> mbuf[(t8+1)&1]
          if (t8 < NSUB - 1) {
            int l = tid - 64, o2 = (t8 + 1) * SUB;
            const float4* src = (const float4*)(tb + (size_t)(o2 + l) * BB + o2);
            float4* dst = (float4*)(mbuf + ((t8 + 1) & 1) * MBUFW + l * MSTR);
#pragma unroll
            for (int j = 0; j < 16; ++j) dst[j] = src[j];
          }
        } else {
          if (t8 < NSUB - 1 && tid >= 256) {
            int t = tid - 256;
            // near-strip: rows sub(t8+1), cols sub(t8)
            const float4* pr = (const float4*)(
                tb + (size_t)((t8 + 1) * SUB + (t >> 2)) * BB + o + (t & 3) * 16);
            nv0 = pr[0]; nv1 = pr[1]; nv2 = pr[2]; nv3 = pr[3];
            if (b > 0) {
              // del7-strip: rows sub(t8+1)
              const float4* sr = (const float4*)(
                  stripG + ((size_t)b * BB + (t8 + 1) * SUB + (t >> 2)) * SUB + (t & 3) * 16);
              sv0 = sr[0]; sv1 = sr[1]; sv2 = sr[2]; sv3 = sr[3];
            }
          }
          if (t8 > 0) {
            // far-pass: apply del(t8-1) to rows beyond sub t8 (waves 2-7)
            for (int r = (t8 + 1) * SUB + (tid - 128); r < BB; r += 384) {
              int c0 = (t8 - 1) * SUB;
              const float4* mr3 = (const float4*)(tb + (size_t)r * BB + c0);
              double acc = sumsL[r];
#pragma unroll
              for (int j = 0; j < SUB / 4; ++j) {
                float4 v = mr3[j];
                acc += (double)(v.x * delL[c0+4*j])   + (double)(v.y * delL[c0+4*j+1]) +
                       (double)(v.z * delL[c0+4*j+2]) + (double)(v.w * delL[c0+4*j+3]);
              }
              sumsL[r] = acc;
            }
          }
        }
        __syncthreads();
      }
      // ---------------- post-block ----------------
      if (pub && tid == 0) st_rlx(&subFlag[b * NSUB + NSUB - 1], 1u);
      dout[uL[tid]] = oldL[tid] + delL[tid];     // exact {0,1} / clamped init
    }
  } else {
    // ================= workers =================
    float* stateL = (float*)poolD;                           // 32 KB
    double* redW = (double*)((char*)poolD + 32768);          // [8][MAXR]
    const int iw = wg - 1;
    const int r0 = (iw * BB) / NWORK, r1 = ((iw + 1) * BB) / NWORK;
    const int cnt = r1 - r0;                                 // 2..3
    for (int i = tid; i < NN; i += TPB) stateL[i] = init[i];
    __syncthreads();

    for (int p = 0; p < NBLK; ++p) {
      // deferred sub-7 state update of block p-2
      if (p >= 2) {
        const u32* f = &subFlag[(p - 2) * NSUB + NSUB - 1];
        if (tid == 0) { while (ld_rlx(f) == 0u) __builtin_amdgcn_s_sleep(1); }
        __syncthreads();
        if (tid < SUB)
          stateL[perm[(p - 2) * BB + 7 * SUB + tid]] +=
              ldf_rlx(&delG[(p - 2) * BB + 7 * SUB + tid]);
        __syncthreads();
      }
      int pc = perm[p * BB + tid];                 // tile col units
      float g[NSUB - 1];                           // sub 0..6 corr strip
      float* tbp = tileD + (size_t)p * BB * BB;

      for (int ri = 0; ri < cnt; ++ri) {
        int unit = perm[p * BB + r0 + ri];
        const float* wrow = w + (size_t)unit * NN;
        const float4* wr4 = (const float4*)wrow;
        const float4* st4 = (const float4*)stateL;
        double acc = 0.0;
#pragma unroll
        for (int k = 0; k < NN / (4 * TPB); ++k) {  // 4 iters
          float4 a = wr4[tid + k * TPB];
          float4 s = st4[tid + k * TPB];
          acc += (double)(a.x * s.x) + (double)(a.y * s.y) +
                 (double)(a.z * s.z) + (double)(a.w * s.w);
        }
        for (int o = 32; o > 0; o >>= 1) acc += __shfl_down(acc, o, 64);
        if (lane == 0) redW[wv * MAXR + ri] = acc;
        stf_rlx(&tbp[(size_t)(r0 + ri) * BB + tid], wrow[pc]);   // tile row
        if (p > 0 && wv == ri) {
#pragma unroll
          for (int t8 = 0; t8 < NSUB - 1; ++t8)
            g[t8] = wrow[perm[(p - 1) * BB + t8 * SUB + lane]];
          // del7-strip -> global (WG0 self-applies it per phase)
          stf_rlx(&stripG[((size_t)p * BB + r0 + ri) * SUB + lane],
                  wrow[perm[(p - 1) * BB + 7 * SUB + lane]]);
        }
      }
      __syncthreads();
      double Sr = 0.0;
      if (wv < cnt) {
#pragma unroll
        for (int k = 0; k < TPB / 64; ++k) Sr += redW[k * MAXR + wv];
      }
      if (p > 0) {
        // incremental corrections, sub-dels 0..6 (per-phase flags)
        double crr = 0.0;
#pragma unroll
        for (int t8 = 0; t8 < NSUB - 1; ++t8) {
          const u32* f = &subFlag[(p - 1) * NSUB + t8];
          if (tid == 0) { while (ld_rlx(f) == 0u) __builtin_amdgcn_s_sleep(1); }
          __syncthreads();
          float dl = ldf_rlx(&delG[(p - 1) * BB + t8 * SUB + lane]);
          if (wv < cnt) crr += (double)(g[t8] * dl);       // exact product
          if (tid < SUB) stateL[perm[(p - 1) * BB + t8 * SUB + tid]] += dl;
        }
        for (int o = 32; o > 0; o >>= 1) crr += __shfl_down(crr, o, 64);
        Sr += crr;
      }
      if (wv < cnt && lane == 0) std_rlx(&S[(size_t)p * BB + r0 + wv], Sr);
      __syncthreads();                     // drain all sc1 stores (vmcnt)
      if (tid == 0) st_rlx(&ack[(size_t)p * NWORK + iw], 1u);
    }
  }
}

extern "C" void kernel_launch(void* const* d_in, const int* in_sizes, int n_in,
                              void* d_out, int out_size, void* d_ws, size_t ws_size,
                              hipStream_t stream) {
  const float* w      = (const float*)d_in[0];
  const float* init   = (const float*)d_in[1];
  const float* clampv = (const float*)d_in[2];
  const float* Tp     = (const float*)d_in[3];
  const int*   perm   = (const int*)d_in[4];
  const float* urand  = (const float*)d_in[5];
  float* dout = (float*)d_out;

  double* S    = (double*)d_ws;                         // NBLK*BB doubles
  float* delG  = (float*)(S + (size_t)NBLK * BB);       // NN
  float* stripG = delG + NN;                            // NBLK*BB*SUB (2 MB)
  float* tileD = stripG + (size_t)NBLK * BB * SUB;      // NBLK*BB*BB (16 MB)
  u32* subFlag = (u32*)(tileD + (size_t)NBLK * BB * BB);   // NBLK*NSUB
  u32* ack     = subFlag + NBLK * NSUB;                    // NBLK*NWORK

  int nflags = NBLK * NSUB + NBLK * NWORK;
  k_init<<<8, 256, 0, stream>>>(subFlag, nflags);

  void* args[] = {(void*)&w, (void*)&init, (void*)&clampv, (void*)&Tp,
                  (void*)&perm, (void*)&urand, (void*)&dout,
                  (void*)&S, (void*)&delG, (void*)&stripG, (void*)&tileD,
                  (void*)&subFlag, (void*)&ack};
  hipLaunchCooperativeKernel((const void*)k_gibbs, dim3(NWG), dim3(TPB),
                             args, 0, stream);
}

// Round 11
// 566.856 us; speedup vs baseline: 1.0525x; 1.0525x over previous
//
#include <hip/hip_runtime.h>
#include <math.h>

// Boltzmann Gibbs sweep N=8192, single cooperative kernel.
// r7 structure (best: 508us) + boundary fix only:
// 16 blocks of BB=512. WG0 scans block b (8 x 64-step serial sub-scans,
// per-phase del publish); 255 workers compute panel dots vs private LDS
// state + gather coupling tile AND a 512x64 del7-strip; workers apply
// sub-dels 0..6 incrementally and ACK AFTER del6 (during WG0's phase 7);
// the del7 correction is applied by WG0 at the block boundary with one
// plain coalesced float4 pass over the strip (del7 read from LDS delL).
// Cross-WG payloads via agent-scope relaxed (sc1) stores; ordering = vmcnt
// drain at __syncthreads + relaxed flag store. No wbl2/inv on the path.
// Decision: u <= sigmoid(s/T) <=> s >= T*log(u/(1-u)); thr fp64,
// POSITION-indexed (lax.scan zips (perm, rand_u)); clamp/state UNIT-indexed.
// All sums fp64; every correction product w*delta is exact in fp32.

#define NN 8192
#define BB 512
#define NBLK 16
#define SUB 64
#define NSUB 8
#define NWG 256
#define NWORK 255
#define TPB 512
#define MAXR 3

typedef unsigned int u32;
typedef unsigned long long u64;

__global__ void k_init(u32* flags, int n) {
  int i = blockIdx.x * blockDim.x + threadIdx.x;
  for (; i < n; i += gridDim.x * blockDim.x) flags[i] = 0;
}

__device__ __forceinline__ u32 ld_rlx(const u32* p) {
  return __hip_atomic_load(p, __ATOMIC_RELAXED, __HIP_MEMORY_SCOPE_AGENT);
}
__device__ __forceinline__ void st_rlx(u32* p, u32 v) {
  __hip_atomic_store(p, v, __ATOMIC_RELAXED, __HIP_MEMORY_SCOPE_AGENT);
}
__device__ __forceinline__ float ldf_rlx(const float* p) {
  return __hip_atomic_load(p, __ATOMIC_RELAXED, __HIP_MEMORY_SCOPE_AGENT);
}
__device__ __forceinline__ void stf_rlx(float* p, float v) {
  __hip_atomic_store(p, v, __ATOMIC_RELAXED, __HIP_MEMORY_SCOPE_AGENT);
}
__device__ __forceinline__ void std_rlx(double* p, double v) {
  __hip_atomic_store(p, v, __ATOMIC_RELAXED, __HIP_MEMORY_SCOPE_AGENT);
}

// wave0: load 64x64 diag tile row into registers
#define LOADM(MARR, T8N) do {                                                  \
  const float4* mr_ = (const float4*)(tb + (size_t)((T8N) * SUB + tid) * BB + (T8N) * SUB); \
  _Pragma("unroll")                                                            \
  for (int j_ = 0; j_ < SUB / 4; ++j_) {                                       \
    float4 v_ = mr_[j_];                                                       \
    MARR[4*j_] = v_.x; MARR[4*j_+1] = v_.y;                                    \
    MARR[4*j_+2] = v_.z; MARR[4*j_+3] = v_.w; }                                \
} while (0)

// wave0: serial 64-step sub-scan
#define CHAIN(MARR, T8C) do {                                                  \
  int row_ = (T8C) * SUB + tid;                                                \
  double sum_ = sumsL[row_], th_ = thrL[row_];                                 \
  float dd1_ = d1L[row_], dd0_ = d0L[row_];                                    \
  float mydel_ = 0.0f;                                                         \
  __builtin_amdgcn_s_setprio(3);                                               \
  _Pragma("unroll")                                                            \
  for (int s_ = 0; s_ < SUB; ++s_) {                                           \
    float down_ = (sum_ >= th_) ? dd1_ : dd0_;                                 \
    float sd_ = __uint_as_float(                                               \
        __builtin_amdgcn_readlane(__float_as_uint(down_), s_));                \
    if (s_ == tid) mydel_ = down_;                                             \
    sum_ += (double)(MARR[s_] * sd_); }                                        \
  __builtin_amdgcn_s_setprio(0);                                               \
  delL[row_] = mydel_;                                                         \
  if (pub) stf_rlx(&delG[b * BB + row_], mydel_);                              \
} while (0)

__global__ __launch_bounds__(TPB) void k_gibbs(
    const float* __restrict__ w, const float* __restrict__ init,
    const float* __restrict__ clampv, const float* __restrict__ Tp,
    const int* __restrict__ perm, const float* __restrict__ urand,
    float* __restrict__ dout, double* __restrict__ S,
    float* __restrict__ delG, float* __restrict__ stripG,
    float* __restrict__ tileD, u32* subFlag, u32* ack) {
  __shared__ float stateL[NN];                     // workers (32 KB)
  __shared__ double sumsL[BB], thrL[BB];           // WG0 (8 KB)
  __shared__ float d1L[BB], d0L[BB], delL[BB], oldL[BB];
  __shared__ int uL[BB];
  __shared__ double redL[TPB / 64][MAXR];
  const int wg = blockIdx.x, tid = threadIdx.x;
  const int wv = tid >> 6, lane = tid & 63;

  if (wg == 0) {
    // ================= producer: serial scans =================
    double T = (double)Tp[0];
    for (int b = 0; b < NBLK; ++b) {
      const bool pub = (b + 1 < NBLK);
      // ---- per-block tables (before the ack wait; overlapped) ----
      int pos = b * BB + tid;                      // TPB == BB
      int unit = perm[pos];
      double uu = (double)urand[pos];
      thrL[tid] = T * log(uu / (1.0 - uu));        // u==0 -> -inf -> always 1
      float old = init[unit];
      bool cl = (clampv[unit] != 0.0f);
      d1L[tid] = cl ? 0.0f : (1.0f - old);         // delta if decision==1
      d0L[tid] = cl ? 0.0f : (0.0f - old);         // delta if decision==0
      oldL[tid] = old;
      uL[tid] = unit;
      // ---- wait: workers acked block b (S[b] 0..6-corrected, tile+strip in L3)
      {
        const u32* slots = ack + (size_t)b * NWORK;
        for (;;) {
          int ok = 1;
          if (tid < NWORK) ok = (ld_rlx(&slots[tid]) != 0u);
          if (__syncthreads_and(ok)) break;
          __builtin_amdgcn_s_sleep(1);
        }
      }
      // S read + del7(b-1) fold (plain coalesced loads; delL still holds b-1)
      {
        double acc = S[(size_t)b * BB + tid];
        if (b > 0) {
          const float4* sp = (const float4*)(stripG + ((size_t)b * BB + tid) * SUB);
#pragma unroll
          for (int k = 0; k < SUB / 4; ++k) {
            float4 v = sp[k];
            acc += (double)(v.x * delL[7 * SUB + 4 * k]) +
                   (double)(v.y * delL[7 * SUB + 4 * k + 1]) +
                   (double)(v.z * delL[7 * SUB + 4 * k + 2]) +
                   (double)(v.w * delL[7 * SUB + 4 * k + 3]);
          }
        }
        sumsL[tid] = acc;
      }
      __syncthreads();
      const float* tb = tileD + (size_t)b * BB * BB;
      float mA[SUB], mB[SUB];
      float4 nv0, nv1, nv2, nv3;           // near-strip prefetch regs (waves 4-7)
      if (tid < SUB) LOADM(mA, 0);

      for (int t8 = 0; t8 < NSUB; ++t8) {
        // ---- A section: publish del(t8-1) flag + register near-fma ----
        if (t8 > 0) {
          if (pub && tid == 0) st_rlx(&subFlag[b * NSUB + (t8 - 1)], 1u);
          if (tid >= 256) {
            int t = tid - 256;                     // 0..255
            int rrow = t8 * SUB + (t >> 2);
            int q = t & 3;
            int c0 = (t8 - 1) * SUB + q * 16;
            double p_ =
                (double)(nv0.x * delL[c0])    + (double)(nv0.y * delL[c0+1]) +
                (double)(nv0.z * delL[c0+2])  + (double)(nv0.w * delL[c0+3]) +
                (double)(nv1.x * delL[c0+4])  + (double)(nv1.y * delL[c0+5]) +
                (double)(nv1.z * delL[c0+6])  + (double)(nv1.w * delL[c0+7]);
            p_ +=
                (double)(nv2.x * delL[c0+8])  + (double)(nv2.y * delL[c0+9]) +
                (double)(nv2.z * delL[c0+10]) + (double)(nv2.w * delL[c0+11]) +
                (double)(nv3.x * delL[c0+12]) + (double)(nv3.y * delL[c0+13]) +
                (double)(nv3.z * delL[c0+14]) + (double)(nv3.w * delL[c0+15]);
            p_ += __shfl_down(p_, 2, 4);
            p_ += __shfl_down(p_, 1, 4);
            if (q == 0) sumsL[rrow] += p_;
          }
        }
        __syncthreads();
        // ---- B section: chain || prefetch || far-pass ----
        if (tid < SUB) {
          if (t8 & 1) { if (t8 < NSUB - 1) LOADM(mA, t8 + 1); CHAIN(mB, t8); }
          else        { if (t8 < NSUB - 1) LOADM(mB, t8 + 1); CHAIN(mA, t8); }
        } else {
          if (t8 < NSUB - 1 && tid >= 256) {
            // prefetch near-strip: rows sub(t8+1), cols sub(t8)
            int t = tid - 256;
            const float4* pr = (const float4*)(
                tb + (size_t)((t8 + 1) * SUB + (t >> 2)) * BB + t8 * SUB + (t & 3) * 16);
            nv0 = pr[0]; nv1 = pr[1]; nv2 = pr[2]; nv3 = pr[3];
          }
          if (t8 > 0) {
            // far-pass: apply del(t8-1) to rows beyond sub t8
            for (int r = (t8 + 1) * SUB + (tid - SUB); r < BB; r += (TPB - SUB)) {
              int c0 = (t8 - 1) * SUB;
              const float4* mr3 = (const float4*)(tb + (size_t)r * BB + c0);
              double acc = sumsL[r];
#pragma unroll
              for (int j = 0; j < SUB / 4; ++j) {
                float4 v = mr3[j];
                acc += (double)(v.x * delL[c0+4*j])   + (double)(v.y * delL[c0+4*j+1]) +
                       (double)(v.z * delL[c0+4*j+2]) + (double)(v.w * delL[c0+4*j+3]);
              }
              sumsL[r] = acc;
            }
          }
        }
        __syncthreads();                            // drains delG stores (vmcnt)
      }
      if (pub && tid == 0) st_rlx(&subFlag[b * NSUB + (NSUB - 1)], 1u);
      dout[uL[tid]] = oldL[tid] + delL[tid];        // exact {0,1} / clamped init
    }
  } else {
    // ================= workers =================
    const int iw = wg - 1;
    const int r0 = (iw * BB) / NWORK, r1 = ((iw + 1) * BB) / NWORK;
    const int cnt = r1 - r0;                        // 2..3
    for (int i = tid; i < NN; i += TPB) stateL[i] = init[i];
    __syncthreads();

    for (int p = 0; p < NBLK; ++p) {
      // deferred sub-7 state update of block p-2
      if (p >= 2) {
        const u32* f = &subFlag[(p - 2) * NSUB + NSUB - 1];
        if (tid == 0) { while (ld_rlx(f) == 0u) __builtin_amdgcn_s_sleep(1); }
        __syncthreads();
        if (tid < SUB)
          stateL[perm[(p - 2) * BB + 7 * SUB + tid]] +=
              ldf_rlx(&delG[(p - 2) * BB + 7 * SUB + tid]);
        __syncthreads();
      }
      int pc = perm[p * BB + tid];                  // tile col units
      float g[NSUB - 1];                            // sub 0..6 corr strip
      float* tbp = tileD + (size_t)p * BB * BB;

      for (int ri = 0; ri < cnt; ++ri) {
        int unit = perm[p * BB + r0 + ri];
        const float* wrow = w + (size_t)unit * NN;
        const float4* wr4 = (const float4*)wrow;
        const float4* st4 = (const float4*)stateL;
        double acc = 0.0;
#pragma unroll
        for (int k = 0; k < NN / (4 * TPB); ++k) {  // 4 iters
          float4 a = wr4[tid + k * TPB];
          float4 s = st4[tid + k * TPB];
          acc += (double)(a.x * s.x) + (double)(a.y * s.y) +
                 (double)(a.z * s.z) + (double)(a.w * s.w);
        }
        for (int o = 32; o > 0; o >>= 1) acc += __shfl_down(acc, o, 64);
        if (lane == 0) redL[wv][ri] = acc;
        stf_rlx(&tbp[(size_t)(r0 + ri) * BB + tid], wrow[pc]);   // tile row
        if (p > 0 && wv == ri) {                    // strips vs block p-1 (L1-hot)
#pragma unroll
          for (int t8 = 0; t8 < NSUB - 1; ++t8)
            g[t8] = wrow[perm[(p - 1) * BB + t8 * SUB + lane]];
          // del7-strip -> global (WG0 folds it at the boundary)
          stf_rlx(&stripG[((size_t)p * BB + r0 + ri) * SUB + lane],
                  wrow[perm[(p - 1) * BB + 7 * SUB + lane]]);
        }
      }
      __syncthreads();
      double Sr = 0.0;
      if (wv < cnt) {
#pragma unroll
        for (int k = 0; k < TPB / 64; ++k) Sr += redL[k][wv];
      }
      if (p > 0) {
        // incremental corrections, sub-dels 0..6 (per-phase flags)
        double crr = 0.0;
#pragma unroll
        for (int t8 = 0; t8 < NSUB - 1; ++t8) {
          const u32* f = &subFlag[(p - 1) * NSUB + t8];
          if (tid == 0) { while (ld_rlx(f) == 0u) __builtin_amdgcn_s_sleep(1); }
          __syncthreads();
          float dl = ldf_rlx(&delG[(p - 1) * BB + t8 * SUB + lane]);
          if (wv < cnt) crr += (double)(g[t8] * dl);       // exact product
          if (tid < SUB) stateL[perm[(p - 1) * BB + t8 * SUB + tid]] += dl;
        }
        for (int o = 32; o > 0; o >>= 1) crr += __shfl_down(crr, o, 64);
        Sr += crr;
      }
      if (wv < cnt && lane == 0) std_rlx(&S[(size_t)p * BB + r0 + wv], Sr);
      __syncthreads();                     // drain all sc1 stores (vmcnt)
      if (tid == 0) st_rlx(&ack[(size_t)p * NWORK + iw], 1u);
    }
  }
}

extern "C" void kernel_launch(void* const* d_in, const int* in_sizes, int n_in,
                              void* d_out, int out_size, void* d_ws, size_t ws_size,
                              hipStream_t stream) {
  const float* w      = (const float*)d_in[0];
  const float* init   = (const float*)d_in[1];
  const float* clampv = (const float*)d_in[2];
  const float* Tp     = (const float*)d_in[3];
  const int*   perm   = (const int*)d_in[4];
  const float* urand  = (const float*)d_in[5];
  float* dout = (float*)d_out;

  double* S    = (double*)d_ws;                         // NBLK*BB doubles
  float* delG  = (float*)(S + (size_t)NBLK * BB);       // NN
  float* stripG = delG + NN;                            // NBLK*BB*SUB (2 MB)
  float* tileD = stripG + (size_t)NBLK * BB * SUB;      // NBLK*BB*BB (16 MB)
  u32* subFlag = (u32*)(tileD + (size_t)NBLK * BB * BB);   // NBLK*NSUB
  u32* ack     = subFlag + NBLK * NSUB;                    // NBLK*NWORK

  int nflags = NBLK * NSUB + NBLK * NWORK;
  k_init<<<8, 256, 0, stream>>>(subFlag, nflags);

  void* args[] = {(void*)&w, (void*)&init, (void*)&clampv, (void*)&Tp,
                  (void*)&perm, (void*)&urand, (void*)&dout,
                  (void*)&S, (void*)&delG, (void*)&stripG, (void*)&tileD,
                  (void*)&subFlag, (void*)&ack};
  hipLaunchCooperativeKernel((const void*)k_gibbs, dim3(NWG), dim3(TPB),
                             args, 0, stream);
}